// Round 12
// baseline (53.607 us; speedup 1.0000x reference)
//
#include <hip/hip_runtime.h>
#include <math.h>

#define K 2048           // time buckets
#define NHB 256          // histogram-role blocks, 1024 thr
#define NWB 256          // focal-role blocks, 1024 thr
#define NB (NHB + NWB)
#define PS_H 6144        // pw float4s per hist block
#define PS_W 10240       // pw float4s per work block (256*(6144+10240) = nw/4)

// ---------------- k1: one pass over everything, deep-batched loads ----------
__global__ __launch_bounds__(1024, 8) void k1(
    const float* __restrict__ tm, const float* __restrict__ h,
    const int* __restrict__ ev, int n,
    const float* __restrict__ rp, const int* __restrict__ rl,
    const float* __restrict__ pw, int nw,
    const float* __restrict__ pb, int nb,
    float* __restrict__ btot, unsigned* __restrict__ bev,
    double* __restrict__ partW, double* __restrict__ partH) {
    __shared__ __align__(16) char smem[16384];
    float*    hist   = (float*)smem;              // [K]
    unsigned* histev = (unsigned*)(smem + 8192);  // [K]
    double*   lds    = (double*)smem;             // [2048] reused after flush
    int bid = blockIdx.x, tid = threadIdx.x;
    double foc = 0.0, reg = 0.0, seh = 0.0;
    int ne = 0;

    const float4* mypw;
    int mycnt;

    if (bid < NHB) {
        // ---- histogram role: 12 independent loads in flight ----
        for (int j = tid; j < K; j += 1024) { hist[j] = 0.f; histev[j] = 0u; }
        __syncthreads();
        const float4* tm4 = (const float4*)tm + (long long)bid * 4096;
        const float4* h4  = (const float4*)h  + (long long)bid * 4096;
        const int4*   ev4 = (const int4*)ev  + (long long)bid * 4096;
        float4 T0 = tm4[tid], T1 = tm4[tid + 1024], T2 = tm4[tid + 2048], T3 = tm4[tid + 3072];
        float4 H0 = h4[tid],  H1 = h4[tid + 1024],  H2 = h4[tid + 2048],  H3 = h4[tid + 3072];
        int4   E0 = ev4[tid], E1 = ev4[tid + 1024], E2 = ev4[tid + 2048], E3 = ev4[tid + 3072];
#define HL(tc, hc, ec)                                                        \
        {                                                                     \
            unsigned b = (unsigned)((tc) * (float)K);                         \
            if (b > K - 1u) b = K - 1u;                                       \
            atomicAdd(&hist[b], __expf(hc));                                  \
            if (ec) { atomicAdd(&histev[b], 1u);                              \
                      seh += (double)(hc); ne += 1; }                         \
        }
        HL(T0.x, H0.x, E0.x) HL(T0.y, H0.y, E0.y) HL(T0.z, H0.z, E0.z) HL(T0.w, H0.w, E0.w)
        HL(T1.x, H1.x, E1.x) HL(T1.y, H1.y, E1.y) HL(T1.z, H1.z, E1.z) HL(T1.w, H1.w, E1.w)
        HL(T2.x, H2.x, E2.x) HL(T2.y, H2.y, E2.y) HL(T2.z, H2.z, E2.z) HL(T2.w, H2.w, E2.w)
        HL(T3.x, H3.x, E3.x) HL(T3.y, H3.y, E3.y) HL(T3.z, H3.z, E3.z) HL(T3.w, H3.w, E3.w)
#undef HL
        __syncthreads();
        for (int j = tid; j < K; j += 1024) {      // flush: ~1M atomics total
            atomicAdd(&btot[j], hist[j]);
            unsigned c = histev[j];
            if (c) atomicAdd(&bev[j], c);
        }
        mypw  = (const float4*)pw + (long long)bid * PS_H;
        mycnt = PS_H;
    } else {
        // ---- focal role: 8 independent loads in flight ----
        int widx = bid - NHB;
        const float4* rp4 = (const float4*)rp + (long long)widx * 4096;
        const int4*   rl4 = (const int4*)rl + (long long)widx * 4096;
        float4 P0 = rp4[tid], P1 = rp4[tid + 1024], P2 = rp4[tid + 2048], P3 = rp4[tid + 3072];
        int4   L0 = rl4[tid], L1 = rl4[tid + 1024], L2 = rl4[tid + 2048], L3 = rl4[tid + 3072];
#define FOC(pc, lc)                                                           \
        {                                                                     \
            float pp = pc; float tt = (float)(lc);                            \
            float ce = fmaxf(pp, 0.f) - pp * tt                               \
                     + __logf(1.f + __expf(-fabsf(pp)));                      \
            float ptv = __expf(-ce); float om = 1.f - ptv;                    \
            foc += (double)((0.25f * tt + 0.75f * (1.f - tt)) * om * om * ce);\
        }
        FOC(P0.x, L0.x) FOC(P0.y, L0.y) FOC(P0.z, L0.z) FOC(P0.w, L0.w)
        FOC(P1.x, L1.x) FOC(P1.y, L1.y) FOC(P1.z, L1.z) FOC(P1.w, L1.w)
        FOC(P2.x, L2.x) FOC(P2.y, L2.y) FOC(P2.z, L2.z) FOC(P2.w, L2.w)
        FOC(P3.x, L3.x) FOC(P3.y, L3.y) FOC(P3.z, L3.z) FOC(P3.w, L3.w)
#undef FOC
        mypw  = (const float4*)pw + (long long)NHB * PS_H + (long long)widx * PS_W;
        mycnt = PS_W;
    }

    // ---- common: pw slice, 5/6-load batches, f32 inner squares ----
#define SQ4(V) {                                                              \
        float s = (V).x * (V).x + (V).y * (V).y                               \
                + (V).z * (V).z + (V).w * (V).w;                              \
        reg += (double)s; }
    if (mycnt == PS_H) {                           // 6 per thread
        float4 V0 = mypw[tid],        V1 = mypw[tid + 1024], V2 = mypw[tid + 2048];
        float4 V3 = mypw[tid + 3072], V4 = mypw[tid + 4096], V5 = mypw[tid + 5120];
        SQ4(V0) SQ4(V1) SQ4(V2) SQ4(V3) SQ4(V4) SQ4(V5)
    } else {                                       // 10 per thread: 5 + 5
        float4 V0 = mypw[tid],        V1 = mypw[tid + 1024], V2 = mypw[tid + 2048];
        float4 V3 = mypw[tid + 3072], V4 = mypw[tid + 4096];
        SQ4(V0) SQ4(V1) SQ4(V2) SQ4(V3) SQ4(V4)
        float4 W0 = mypw[tid + 5120], W1 = mypw[tid + 6144], W2 = mypw[tid + 7168];
        float4 W3 = mypw[tid + 8192], W4 = mypw[tid + 9216];
        SQ4(W0) SQ4(W1) SQ4(W2) SQ4(W3) SQ4(W4)
    }
    if (bid == NHB) {                              // pb: exactly 1024 float4s
        int nb4 = nb >> 2;
        if (tid < nb4) {
            float4 v = ((const float4*)pb)[tid];
            SQ4(v)
        }
    }
#undef SQ4

    __syncthreads();                               // LDS hist no longer needed
    lds[tid] = foc; lds[1024 + tid] = reg; __syncthreads();
    for (int s = 512; s > 0; s >>= 1) {
        if (tid < s) { lds[tid] += lds[tid + s]; lds[1024 + tid] += lds[1024 + tid + s]; }
        __syncthreads();
    }
    if (tid == 0) { partW[bid * 2 + 0] = lds[0]; partW[bid * 2 + 1] = lds[1024]; }
    if (bid < NHB) {
        __syncthreads();
        lds[tid] = seh; lds[1024 + tid] = (double)ne; __syncthreads();
        for (int s = 512; s > 0; s >>= 1) {
            if (tid < s) { lds[tid] += lds[tid + s]; lds[1024 + tid] += lds[1024 + tid + s]; }
            __syncthreads();
        }
        if (tid == 0) { partH[bid * 2 + 0] = lds[0]; partH[bid * 2 + 1] = lds[1024]; }
    }
}

// ---------------- kTail: scan + dot + reduce + combine -----------------------
__global__ __launch_bounds__(1024) void kTail(
    const float* __restrict__ btot, const unsigned* __restrict__ bev,
    const double* __restrict__ partW, const double* __restrict__ partH,
    const float* __restrict__ lsv, const float* __restrict__ lrv,
    const float* __restrict__ lgv, int n, float* __restrict__ out) {
    __shared__ double lds[2048];
    int tid = threadIdx.x;
    float v0 = btot[2 * tid], v1 = btot[2 * tid + 1];
    unsigned c0 = bev[2 * tid], c1 = bev[2 * tid + 1];
    lds[tid] = (double)v0 + (double)v1; __syncthreads();
    for (int off = 1; off < 1024; off <<= 1) {
        double a = (tid >= off) ? lds[tid - off] : 0.0;
        __syncthreads();
        lds[tid] += a;
        __syncthreads();
    }
    double run = (tid == 0) ? 0.0 : lds[tid - 1];
    double r0 = run + (double)v0;
    double r1 = r0 + (double)v1;
    double dot = 0.0;
    if (c0) dot += (double)c0 * log(r0);
    if (c1) dot += (double)c1 * log(r1);
    __syncthreads();

    double foc = 0.0, reg = 0.0, seh = 0.0, nev = 0.0;
    if (tid < NB)  { foc = partW[tid * 2 + 0]; reg = partW[tid * 2 + 1]; }
    if (tid < NHB) { seh = partH[tid * 2 + 0]; nev = partH[tid * 2 + 1]; }

    lds[tid] = dot; lds[1024 + tid] = foc; __syncthreads();
    for (int s = 512; s > 0; s >>= 1) {
        if (tid < s) { lds[tid] += lds[tid + s]; lds[1024 + tid] += lds[1024 + tid + s]; }
        __syncthreads();
    }
    double dotT = lds[0], focT = lds[1024]; __syncthreads();
    lds[tid] = reg; lds[1024 + tid] = seh; __syncthreads();
    for (int s = 512; s > 0; s >>= 1) {
        if (tid < s) { lds[tid] += lds[tid + s]; lds[1024 + tid] += lds[1024 + tid + s]; }
        __syncthreads();
    }
    double regT = lds[0], sehT = lds[1024]; __syncthreads();
    lds[tid] = nev; __syncthreads();
    for (int s = 512; s > 0; s >>= 1) {
        if (tid < s) lds[tid] += lds[tid + s];
        __syncthreads();
    }
    if (tid == 0) {
        double neT = lds[0];
        double cox = sehT - dotT;                  // Σ_events (h - logS)
        double surv = -cox / (neT + 1e-8);
        double rec = focT / (double)n;
        double rg = 1e-4 * regT;
        double a = (double)lsv[0], b = (double)lrv[0], c = (double)lgv[0];
        double sp = exp(-a), rpv = exp(-b), gp = exp(-c);
        double total = sp * surv + rpv * rec + gp * rg + a + b + c;
        out[0] = (float)total;
        out[1] = (float)surv;
        out[2] = (float)rec;
        out[3] = (float)rg;
        out[4] = (float)sp;
        out[5] = (float)rpv;
    }
}

extern "C" void kernel_launch(void* const* d_in, const int* in_sizes, int n_in,
                              void* d_out, int out_size, void* d_ws, size_t ws_size,
                              hipStream_t stream) {
    const float* h   = (const float*)d_in[0];
    const float* rp  = (const float*)d_in[1];
    const float* tm  = (const float*)d_in[2];
    const int*   ev  = (const int*)d_in[3];
    const int*   rl  = (const int*)d_in[4];
    const float* pw  = (const float*)d_in[5];
    const float* pb  = (const float*)d_in[6];
    const float* lsv = (const float*)d_in[7];
    const float* lrv = (const float*)d_in[8];
    const float* lgv = (const float*)d_in[9];
    int n  = in_sizes[0];
    int nw = in_sizes[5];
    int nb = in_sizes[6];
    float* out = (float*)d_out;

    float*    btot  = (float*)d_ws;                // K floats
    unsigned* bev   = (unsigned*)(btot + K);       // K uints
    double*   partW = (double*)(bev + K);          // NB*2 doubles
    double*   partH = partW + 2 * NB;              // NHB*2 doubles

    hipMemsetAsync(btot, 0, (size_t)K * 8, stream);   // btot + bev
    k1<<<NB, 1024, 0, stream>>>(tm, h, ev, n, rp, rl, pw, nw, pb, nb,
                                btot, bev, partW, partH);
    kTail<<<1, 1024, 0, stream>>>(btot, bev, partW, partH, lsv, lrv, lgv, n, out);
}